// Round 10
// baseline (205.478 us; speedup 1.0000x reference)
//
#include <hip/hip_runtime.h>
#include <hip/hip_bf16.h>
#include <math.h>

// ---------------------------------------------------------------------------
// GraphSAGE inference, bf16 MFMA pipeline.
//   h1 = relu([aggr(x)|x] @ [w1l;w1r] + b1)      (MFMA, K=256)
//   h2 = relu([aggr(h1)|h1] @ [w2l;w2r] + b2)
//   out = log_softmax(mean_pool(h2) @ wf + bf)
// R1: atomics -> CSR+gather. R2: bf16 MFMA GEMM, packed weights.
// R3: gather MLP. R4: atomic-free localized CSR fill. R5: segmented pool.
// R6: fused layer REGRESSED -> reverted. R7: column-class gather REGRESSED
//     -> reverted. R8: uint4 gather (16 lanes/row, 4 edge slots).
// R9: XCD-localized atomics for CSR build: class-partitioned degree
//     histogram (fire-and-forget) + cursor-based fill; rank array removed.
//     deg_rank's cross-XCD atomic line bouncing was 40us.
// ---------------------------------------------------------------------------

#define FDIM 128

typedef __attribute__((ext_vector_type(8))) short bf16x8;
typedef __attribute__((ext_vector_type(4))) float f32x4;

__device__ inline unsigned short f2bf(float f) {
    union { float f; unsigned u; } v; v.f = f;
    unsigned r = v.u + 0x7fff + ((v.u >> 16) & 1);   // RNE
    return (unsigned short)(r >> 16);
}
__device__ inline float bf2f(unsigned short b) {
    union { unsigned u; float f; } v; v.u = ((unsigned)b) << 16;
    return v.f;
}

// unpack uint4 (8 bf16) and accumulate into 8 f32
__device__ inline void acc8(float* a, uint4 w) {
    union { unsigned u; float f; } t;
    t.u = w.x << 16;          a[0] += t.f;
    t.u = w.x & 0xffff0000u;  a[1] += t.f;
    t.u = w.y << 16;          a[2] += t.f;
    t.u = w.y & 0xffff0000u;  a[3] += t.f;
    t.u = w.z << 16;          a[4] += t.f;
    t.u = w.z & 0xffff0000u;  a[5] += t.f;
    t.u = w.w << 16;          a[6] += t.f;
    t.u = w.w & 0xffff0000u;  a[7] += t.f;
}
__device__ inline void acc8m(float* a, uint4 w, float m) {
    union { unsigned u; float f; } t;
    t.u = w.x << 16;          a[0] = fmaf(m, t.f, a[0]);
    t.u = w.x & 0xffff0000u;  a[1] = fmaf(m, t.f, a[1]);
    t.u = w.y << 16;          a[2] = fmaf(m, t.f, a[2]);
    t.u = w.y & 0xffff0000u;  a[3] = fmaf(m, t.f, a[3]);
    t.u = w.z << 16;          a[4] = fmaf(m, t.f, a[4]);
    t.u = w.z & 0xffff0000u;  a[5] = fmaf(m, t.f, a[5]);
    t.u = w.w << 16;          a[6] = fmaf(m, t.f, a[6]);
    t.u = w.w & 0xffff0000u;  a[7] = fmaf(m, t.f, a[7]);
}

// --- prep: f32->bf16 cvt | weight packs (deg moved out) --------------------
__global__ __launch_bounds__(256) void prep_k(
        const float* __restrict__ x, unsigned short* __restrict__ xb, int n4,
        const float* __restrict__ w1l, const float* __restrict__ w1r,
        unsigned short* __restrict__ wp1,
        const float* __restrict__ w2l, const float* __restrict__ w2r,
        unsigned short* __restrict__ wp2,
        int nbC) {
    int bid = blockIdx.x, tid = threadIdx.x;
    if (bid < nbC) {
        int i = bid * 256 + tid;
        if (i < n4) {
            float4 v = ((const float4*)x)[i];
            ushort4 o;
            o.x = f2bf(v.x); o.y = f2bf(v.y); o.z = f2bf(v.z); o.w = f2bf(v.w);
            ((ushort4*)xb)[i] = o;
        }
    } else {
        int pb = bid - nbC;                       // 0..31
        const float* wl = (pb < 16) ? w1l : w2l;
        const float* wr = (pb < 16) ? w1r : w2r;
        unsigned short* wp = (pb < 16) ? wp1 : wp2;
        int t = (pb & 15) * 256 + tid;            // 0..4095
        int lane = t & 63, s = (t >> 6) & 7, nt = t >> 9;
        int kbase = s * 32 + ((lane >> 4) * 8);
        int c = nt * 16 + (lane & 15);
        unsigned short tmp[8];
        #pragma unroll
        for (int j = 0; j < 8; ++j) {
            int k = kbase + j;
            float w = (k < 128) ? wl[k * 128 + c] : wr[(k - 128) * 128 + c];
            tmp[j] = f2bf(w);
        }
        ushort4 lo, hi;
        lo.x = tmp[0]; lo.y = tmp[1]; lo.z = tmp[2]; lo.w = tmp[3];
        hi.x = tmp[4]; hi.y = tmp[5]; hi.z = tmp[6]; hi.w = tmp[7];
        ((ushort4*)wp)[t * 2 + 0] = lo;
        ((ushort4*)wp)[t * 2 + 1] = hi;
    }
}

// --- class-partitioned degree histogram ------------------------------------
// Class (blockIdx&7) owns dst range [cls*rngSize, +rngSize); under the
// round-robin block->XCD heuristic its deg lines stay in one XCD's L2, so
// the atomics never bounce cross-XCD. Fire-and-forget (no return value).
// Correct for any mapping: (class, edge) pairs partition increments exactly.
__global__ __launch_bounds__(256) void deg_swz_k(
        const int* __restrict__ dst, int* __restrict__ deg, int nE, int rngSize) {
    int cls = blockIdx.x & 7;
    int lo = cls * rngSize, hi = lo + rngSize;
    int nb = gridDim.x >> 3;
    int bi = blockIdx.x >> 3;
    for (int e = bi * 256 + threadIdx.x; e < nE; e += nb * 256) {
        int d = dst[e];
        if (d >= lo && d < hi) atomicAdd(&deg[d], 1);
    }
}

__global__ __launch_bounds__(256) void scan1_k(const int* __restrict__ deg,
                                               int* __restrict__ rowstart,
                                               int* __restrict__ bsum, int n) {
    __shared__ int s[256];
    int tid = threadIdx.x;
    int i = blockIdx.x * 256 + tid;
    int v = (i < n) ? deg[i] : 0;
    s[tid] = v;
    __syncthreads();
    for (int off = 1; off < 256; off <<= 1) {
        int t = (tid >= off) ? s[tid - off] : 0;
        __syncthreads();
        s[tid] += t;
        __syncthreads();
    }
    if (i < n) rowstart[i] = s[tid] - v;
    if (tid == 255) bsum[blockIdx.x] = s[255];
}

__global__ __launch_bounds__(256) void scan2_k(int* __restrict__ bsum, int nb) {
    __shared__ int s[256];
    int tid = threadIdx.x;
    int v = (tid < nb) ? bsum[tid] : 0;
    s[tid] = v;
    __syncthreads();
    for (int off = 1; off < 256; off <<= 1) {
        int t = (tid >= off) ? s[tid - off] : 0;
        __syncthreads();
        s[tid] += t;
        __syncthreads();
    }
    if (tid < nb) bsum[tid] = s[tid] - v;
}

// final rowstart += block offset; also seed cursor = rowstart
__global__ void addoff_k(int* __restrict__ rowstart, const int* __restrict__ bsum,
                         int* __restrict__ cursor, int n) {
    int i = blockIdx.x * blockDim.x + threadIdx.x;
    if (i < n) {
        int v = rowstart[i] + bsum[blockIdx.x];
        rowstart[i] = v;
        cursor[i] = v;
    }
}

// --- class-partitioned cursor fill: csr[atomicAdd(cursor[d])] = src --------
// cursor lines and the csr window are XCD-local under the heuristic.
__global__ __launch_bounds__(256) void fill_cur_k(
        const int* __restrict__ src, const int* __restrict__ dst,
        int* __restrict__ cursor, int* __restrict__ csr, int nE, int rngSize) {
    int cls = blockIdx.x & 7;
    int lo = cls * rngSize, hi = lo + rngSize;
    int nb = gridDim.x >> 3;
    int bi = blockIdx.x >> 3;
    for (int e = bi * 256 + threadIdx.x; e < nE; e += nb * 256) {
        int d = dst[e];
        if (d >= lo && d < hi) {
            int p = atomicAdd(&cursor[d], 1);
            csr[p] = src[e];
        }
    }
}

// --- uint4 gather-mean: one wave per node ----------------------------------
// lane = (edge slot es 0..3) x (col slot cs 0..15, 16B each -> 256B row).
// Main loop: 16 edges/iter, NO masking, 4 x uint4 feat loads + csr prefetch.
__global__ __launch_bounds__(256) void gather_v4_k(
        const uint4* __restrict__ feat,           // [n][16] uint4 (256B rows)
        const int* __restrict__ csr, const int* __restrict__ rowstart,
        const int* __restrict__ deg, uint4* __restrict__ outr, int n) {
    int node = blockIdx.x * 4 + (threadIdx.x >> 6);
    if (node >= n) return;
    int lane = threadIdx.x & 63;
    int es = lane >> 4;                           // edge slot
    int cs = lane & 15;                           // uint4 col slot
    int s0 = rowstart[node], dc = deg[node];

    float acc[8] = {0.f, 0.f, 0.f, 0.f, 0.f, 0.f, 0.f, 0.f};
    int base = 0;
    int i0 = 0, i1 = 0, i2 = 0, i3 = 0;
    if (base + 16 <= dc) {
        i0 = csr[s0 + es];
        i1 = csr[s0 + 4 + es];
        i2 = csr[s0 + 8 + es];
        i3 = csr[s0 + 12 + es];
    }
    while (base + 16 <= dc) {
        uint4 w0 = feat[(size_t)i0 * 16 + cs];
        uint4 w1 = feat[(size_t)i1 * 16 + cs];
        uint4 w2 = feat[(size_t)i2 * 16 + cs];
        uint4 w3 = feat[(size_t)i3 * 16 + cs];
        base += 16;
        if (base + 16 <= dc) {                    // prefetch next indices
            i0 = csr[s0 + base + es];
            i1 = csr[s0 + base + 4 + es];
            i2 = csr[s0 + base + 8 + es];
            i3 = csr[s0 + base + 12 + es];
        }
        acc8(acc, w0);
        acc8(acc, w1);
        acc8(acc, w2);
        acc8(acc, w3);
    }
    if (base < dc) {                              // masked tail
        int c = dc - 1;
        int e0 = base + es, e1 = base + 4 + es, e2 = base + 8 + es, e3 = base + 12 + es;
        int t0 = csr[s0 + min(e0, c)];
        int t1 = csr[s0 + min(e1, c)];
        int t2 = csr[s0 + min(e2, c)];
        int t3 = csr[s0 + min(e3, c)];
        uint4 w0 = feat[(size_t)t0 * 16 + cs];
        uint4 w1 = feat[(size_t)t1 * 16 + cs];
        uint4 w2 = feat[(size_t)t2 * 16 + cs];
        uint4 w3 = feat[(size_t)t3 * 16 + cs];
        acc8m(acc, w0, (e0 < dc) ? 1.0f : 0.0f);
        acc8m(acc, w1, (e1 < dc) ? 1.0f : 0.0f);
        acc8m(acc, w2, (e2 < dc) ? 1.0f : 0.0f);
        acc8m(acc, w3, (e3 < dc) ? 1.0f : 0.0f);
    }

    // reduce across the 4 edge slots (lane bits 4,5)
    #pragma unroll
    for (int k = 0; k < 8; ++k) {
        acc[k] += __shfl_xor(acc[k], 16, 64);
        acc[k] += __shfl_xor(acc[k], 32, 64);
    }

    if (es == 0) {
        float inv = (dc > 0) ? 1.0f / (float)dc : 0.0f;
        uint4 o;
        o.x = ((unsigned)f2bf(acc[1] * inv) << 16) | (unsigned)f2bf(acc[0] * inv);
        o.y = ((unsigned)f2bf(acc[3] * inv) << 16) | (unsigned)f2bf(acc[2] * inv);
        o.z = ((unsigned)f2bf(acc[5] * inv) << 16) | (unsigned)f2bf(acc[4] * inv);
        o.w = ((unsigned)f2bf(acc[7] * inv) << 16) | (unsigned)f2bf(acc[6] * inv);
        outr[(size_t)node * 16 + cs] = o;
    }
}

// --- fused SAGE GEMM: out = relu([A|R] @ Wpack + bias), bf16 MFMA ----------
__global__ __launch_bounds__(256) void gemm_mfma_k(
        const unsigned short* __restrict__ A,     // aggr [n][128] bf16
        const unsigned short* __restrict__ R,     // root [n][128] bf16
        const unsigned short* __restrict__ wp,    // packed weights
        const float* __restrict__ bias,           // [128] f32
        unsigned short* __restrict__ outp,        // [n][128] bf16
        int n) {
    int tid = threadIdx.x;
    int wave = tid >> 6, lane = tid & 63;
    int rowTile = blockIdx.x * 64 + wave * 16;
    int lrow = lane & 15, lk = lane >> 4;

    int arow = rowTile + lrow;
    if (arow >= n) arow = n - 1;                  // clamp; stores are guarded

    bf16x8 a[8];
    const unsigned short* abase = A + (size_t)arow * FDIM + lk * 8;
    const unsigned short* rbase = R + (size_t)arow * FDIM + lk * 8;
    #pragma unroll
    for (int s = 0; s < 4; ++s) a[s] = *(const bf16x8*)(abase + s * 32);
    #pragma unroll
    for (int s = 0; s < 4; ++s) a[4 + s] = *(const bf16x8*)(rbase + s * 32);

    const bf16x8* bp = (const bf16x8*)wp;
    int ocol = lane & 15;
    int orow0 = rowTile + (lane >> 4) * 4;

    #pragma unroll
    for (int nt = 0; nt < 8; ++nt) {
        float bv = bias[nt * 16 + ocol];
        f32x4 acc = {bv, bv, bv, bv};
        #pragma unroll
        for (int s = 0; s < 8; ++s) {
            bf16x8 b = bp[(nt * 8 + s) * 64 + lane];
            acc = __builtin_amdgcn_mfma_f32_16x16x32_bf16(a[s], b, acc, 0, 0, 0);
        }
        #pragma unroll
        for (int r = 0; r < 4; ++r) {
            int orow = orow0 + r;
            if (orow < n) {
                float v = fmaxf(acc[r], 0.0f);
                outp[(size_t)orow * FDIM + nt * 16 + ocol] = f2bf(v);
            }
        }
    }
}

// --- segmented global mean pool: 64 nodes/block, batch sorted --------------
__global__ __launch_bounds__(256) void pool_seg_k(
        const unsigned short* __restrict__ h,     // [nN][128] bf16
        const int* __restrict__ batch,
        float* __restrict__ gsum, int* __restrict__ gcnt, int nN) {
    __shared__ int bw[64];
    __shared__ float red[8][32][4];
    int base = blockIdx.x * 64;
    if (base >= nN) return;
    int tid = threadIdx.x;
    int rg = tid >> 5, cs = tid & 31;
    int cnt = min(64, nN - base);
    if (tid < 64) bw[tid] = batch[min(base + tid, nN - 1)];
    __syncthreads();
    int g0 = bw[0], g1 = bw[cnt - 1];

    for (int g = g0; g <= g1; ++g) {
        int s = 0;
        while (s < cnt && bw[s] < g) ++s;
        int e = s;
        while (e < cnt && bw[e] == g) ++e;

        float a0 = 0.f, a1 = 0.f, a2 = 0.f, a3 = 0.f;
        for (int i = s + rg; i < e; i += 8) {
            uint2 v = ((const uint2*)(h + (size_t)(base + i) * FDIM))[cs];
            a0 += bf2f((unsigned short)(v.x & 0xffff));
            a1 += bf2f((unsigned short)(v.x >> 16));
            a2 += bf2f((unsigned short)(v.y & 0xffff));
            a3 += bf2f((unsigned short)(v.y >> 16));
        }
        red[rg][cs][0] = a0; red[rg][cs][1] = a1;
        red[rg][cs][2] = a2; red[rg][cs][3] = a3;
        __syncthreads();
        if (rg == 0 && e > s) {
            #pragma unroll
            for (int r = 1; r < 8; ++r) {
                a0 += red[r][cs][0]; a1 += red[r][cs][1];
                a2 += red[r][cs][2]; a3 += red[r][cs][3];
            }
            float* go = gsum + (size_t)g * FDIM + cs * 4;
            atomicAdd(go + 0, a0);
            atomicAdd(go + 1, a1);
            atomicAdd(go + 2, a2);
            atomicAdd(go + 3, a3);
            if (cs == 0) atomicAdd(&gcnt[g], e - s);
        }
        __syncthreads();
    }
}

// --- head: logits = mean @ wf + bf ; log_softmax ---------------------------
__global__ __launch_bounds__(128) void head_k(const float* __restrict__ gsum,
                                              const int* __restrict__ gcnt,
                                              const float* __restrict__ wf,
                                              const float* __restrict__ bf,
                                              float* __restrict__ out, int nG) {
    int g = blockIdx.x;
    if (g >= nG) return;
    __shared__ float row[FDIM];
    int tid = threadIdx.x;
    float inv = 1.0f / fmaxf((float)gcnt[g], 1.0f);
    row[tid] = gsum[(size_t)g * FDIM + tid] * inv;
    __syncthreads();

    float logit = -1e30f;
    if (tid < 16) {
        logit = bf[tid];
        for (int k = 0; k < FDIM; ++k) logit += row[k] * wf[k * 16 + tid];
    }
    float m = logit;
    for (int off = 8; off >= 1; off >>= 1) m = fmaxf(m, __shfl_xor(m, off, 64));
    float ev = (tid < 16) ? expf(logit - m) : 0.0f;
    float sum = ev;
    for (int off = 8; off >= 1; off >>= 1) sum += __shfl_xor(sum, off, 64);
    if (tid < 16) out[(size_t)g * 16 + tid] = logit - m - logf(sum);
}

extern "C" void kernel_launch(void* const* d_in, const int* in_sizes, int n_in,
                              void* d_out, int out_size, void* d_ws, size_t ws_size,
                              hipStream_t stream) {
    const float* x    = (const float*)d_in[0];
    const int*   ei   = (const int*)d_in[1];
    const int*   batch= (const int*)d_in[2];
    const float* w1l  = (const float*)d_in[3];
    const float* b1   = (const float*)d_in[4];
    const float* w1r  = (const float*)d_in[5];
    const float* w2l  = (const float*)d_in[6];
    const float* b2   = (const float*)d_in[7];
    const float* w2r  = (const float*)d_in[8];
    const float* wf   = (const float*)d_in[9];
    const float* bf   = (const float*)d_in[10];
    float* out = (float*)d_out;

    const int N = in_sizes[0] / FDIM;
    const int E = in_sizes[1] / 2;
    const int G = out_size / 16;
    const int* src = ei;
    const int* dst = ei + E;
    const int NB = (N + 255) / 256;              // <= 256 for scan2_k

    // --- workspace layout ---
    char* ws = (char*)d_ws;
    size_t off = 0;
    auto alloc = [&](size_t bytes) { void* p = ws + off; off = (off + bytes + 255) & ~(size_t)255; return p; };
    unsigned short* xb   = (unsigned short*)alloc((size_t)N * FDIM * 2); // also h2
    unsigned short* aggr = (unsigned short*)alloc((size_t)N * FDIM * 2);
    unsigned short* h1   = (unsigned short*)alloc((size_t)N * FDIM * 2);
    unsigned short* wp1  = (unsigned short*)alloc(8 * 8 * 64 * 8 * 2);
    unsigned short* wp2  = (unsigned short*)alloc(8 * 8 * 64 * 8 * 2);
    int* deg      = (int*)alloc((size_t)N * sizeof(int));
    int* rowstart = (int*)alloc((size_t)N * sizeof(int));
    int* cursor   = (int*)alloc((size_t)N * sizeof(int));
    int* bsum     = (int*)alloc(256 * sizeof(int));
    int* csr      = (int*)alloc((size_t)E * sizeof(int));
    float* gsum   = (float*)alloc((size_t)G * FDIM * sizeof(float));
    int*   gcnt   = (int*)alloc((size_t)G * sizeof(int));
    unsigned short* h2 = xb;                      // xb dead once h2 is written

    // --- zero accumulators ---
    hipMemsetAsync(deg, 0, (size_t)N * sizeof(int), stream);
    hipMemsetAsync(gsum, 0, (size_t)G * FDIM * sizeof(float), stream);
    hipMemsetAsync(gcnt, 0, (size_t)G * sizeof(int), stream);

    const int rngSize = (N + 7) / 8;

    // --- prep (cvt + packs) and localized degree histogram ---
    const int nbC = (N * FDIM / 4 + 255) / 256;
    prep_k<<<nbC + 32, 256, 0, stream>>>(x, xb, N * FDIM / 4,
                                         w1l, w1r, wp1, w2l, w2r, wp2, nbC);
    deg_swz_k<<<2048, 256, 0, stream>>>(dst, deg, E, rngSize);

    // --- CSR offsets + localized cursor fill ---
    scan1_k<<<NB, 256, 0, stream>>>(deg, rowstart, bsum, N);
    scan2_k<<<1, 256, 0, stream>>>(bsum, NB);
    addoff_k<<<NB, 256, 0, stream>>>(rowstart, bsum, cursor, N);
    fill_cur_k<<<2048, 256, 0, stream>>>(src, dst, cursor, csr, E, rngSize);

    // --- layer 1 ---
    gather_v4_k<<<(N + 3) / 4, 256, 0, stream>>>((const uint4*)xb, csr, rowstart, deg,
                                                 (uint4*)aggr, N);
    gemm_mfma_k<<<(N + 63) / 64, 256, 0, stream>>>(aggr, xb, wp1, b1, h1, N);

    // --- layer 2 ---
    gather_v4_k<<<(N + 3) / 4, 256, 0, stream>>>((const uint4*)h1, csr, rowstart, deg,
                                                 (uint4*)aggr, N);
    gemm_mfma_k<<<(N + 63) / 64, 256, 0, stream>>>(aggr, h1, wp2, b2, h2, N);

    // --- pool + head ---
    pool_seg_k<<<(N + 63) / 64, 256, 0, stream>>>(h2, batch, gsum, gcnt, N);
    head_k<<<G, 128, 0, stream>>>(gsum, gcnt, wf, bf, out, G);
}

// Round 11
// 175.540 us; speedup vs baseline: 1.1705x; 1.1705x over previous
//
#include <hip/hip_runtime.h>
#include <hip/hip_bf16.h>
#include <math.h>

// ---------------------------------------------------------------------------
// GraphSAGE inference, bf16 MFMA pipeline.
//   h1 = relu([aggr(x)|x] @ [w1l;w1r] + b1)      (MFMA, K=256)
//   h2 = relu([aggr(h1)|h1] @ [w2l;w2r] + b2)
//   out = log_softmax(mean_pool(h2) @ wf + bf)
// R1: atomics -> CSR+gather. R2: bf16 MFMA GEMM, packed weights.
// R3: gather MLP. R4: atomic-free localized CSR fill. R5: segmented pool.
// R6: fused layer REGRESSED -> reverted. R7: column-class gather REGRESSED
//     -> reverted. R8: uint4 gather. R9: cursor fill REGRESSED -> reverted.
// R10: R8 base + privatized rank: deg8[8][N] class-replicated counters
//      (class = edge-chunk (e>>8)&7) cut per-line atomic contention 8x;
//      fill stays atomic-free via base8[node][class] offsets.
// ---------------------------------------------------------------------------

#define FDIM 128

typedef __attribute__((ext_vector_type(8))) short bf16x8;
typedef __attribute__((ext_vector_type(4))) float f32x4;

__device__ inline unsigned short f2bf(float f) {
    union { float f; unsigned u; } v; v.f = f;
    unsigned r = v.u + 0x7fff + ((v.u >> 16) & 1);   // RNE
    return (unsigned short)(r >> 16);
}
__device__ inline float bf2f(unsigned short b) {
    union { unsigned u; float f; } v; v.u = ((unsigned)b) << 16;
    return v.f;
}

// unpack uint4 (8 bf16) and accumulate into 8 f32
__device__ inline void acc8(float* a, uint4 w) {
    union { unsigned u; float f; } t;
    t.u = w.x << 16;          a[0] += t.f;
    t.u = w.x & 0xffff0000u;  a[1] += t.f;
    t.u = w.y << 16;          a[2] += t.f;
    t.u = w.y & 0xffff0000u;  a[3] += t.f;
    t.u = w.z << 16;          a[4] += t.f;
    t.u = w.z & 0xffff0000u;  a[5] += t.f;
    t.u = w.w << 16;          a[6] += t.f;
    t.u = w.w & 0xffff0000u;  a[7] += t.f;
}
__device__ inline void acc8m(float* a, uint4 w, float m) {
    union { unsigned u; float f; } t;
    t.u = w.x << 16;          a[0] = fmaf(m, t.f, a[0]);
    t.u = w.x & 0xffff0000u;  a[1] = fmaf(m, t.f, a[1]);
    t.u = w.y << 16;          a[2] = fmaf(m, t.f, a[2]);
    t.u = w.y & 0xffff0000u;  a[3] = fmaf(m, t.f, a[3]);
    t.u = w.z << 16;          a[4] = fmaf(m, t.f, a[4]);
    t.u = w.z & 0xffff0000u;  a[5] = fmaf(m, t.f, a[5]);
    t.u = w.w << 16;          a[6] = fmaf(m, t.f, a[6]);
    t.u = w.w & 0xffff0000u;  a[7] = fmaf(m, t.f, a[7]);
}

// --- merged prep: privatized deg/rank | f32->bf16 cvt | weight packs -------
// Edge blocks (bid < nbE): class c = bid&7; rank[e] = atomicAdd(deg8[c][dst]).
// 8 private counter replicas -> 8x more lines, 8x less per-line contention.
__global__ __launch_bounds__(256) void prep_k(
        const int* __restrict__ dst, int* __restrict__ deg8, int* __restrict__ rank,
        int nE, int N,
        const float* __restrict__ x, unsigned short* __restrict__ xb, int n4,
        const float* __restrict__ w1l, const float* __restrict__ w1r,
        unsigned short* __restrict__ wp1,
        const float* __restrict__ w2l, const float* __restrict__ w2r,
        unsigned short* __restrict__ wp2,
        int nbE, int nbC) {
    int bid = blockIdx.x, tid = threadIdx.x;
    if (bid < nbE) {
        int e = bid * 256 + tid;
        if (e < nE) {
            int c = bid & 7;
            rank[e] = atomicAdd(&deg8[(size_t)c * N + dst[e]], 1);
        }
    } else if (bid < nbE + nbC) {
        int i = (bid - nbE) * 256 + tid;
        if (i < n4) {
            float4 v = ((const float4*)x)[i];
            ushort4 o;
            o.x = f2bf(v.x); o.y = f2bf(v.y); o.z = f2bf(v.z); o.w = f2bf(v.w);
            ((ushort4*)xb)[i] = o;
        }
    } else {
        int pb = bid - nbE - nbC;                 // 0..31
        const float* wl = (pb < 16) ? w1l : w2l;
        const float* wr = (pb < 16) ? w1r : w2r;
        unsigned short* wp = (pb < 16) ? wp1 : wp2;
        int t = (pb & 15) * 256 + tid;            // 0..4095
        int lane = t & 63, s = (t >> 6) & 7, nt = t >> 9;
        int kbase = s * 32 + ((lane >> 4) * 8);
        int c = nt * 16 + (lane & 15);
        unsigned short tmp[8];
        #pragma unroll
        for (int j = 0; j < 8; ++j) {
            int k = kbase + j;
            float w = (k < 128) ? wl[k * 128 + c] : wr[(k - 128) * 128 + c];
            tmp[j] = f2bf(w);
        }
        ushort4 lo, hi;
        lo.x = tmp[0]; lo.y = tmp[1]; lo.z = tmp[2]; lo.w = tmp[3];
        hi.x = tmp[4]; hi.y = tmp[5]; hi.z = tmp[6]; hi.w = tmp[7];
        ((ushort4*)wp)[t * 2 + 0] = lo;
        ((ushort4*)wp)[t * 2 + 1] = hi;
    }
}

// --- scan over total degree; emit deg, per-node class prefixes -------------
// base8[i*8+c] gets the class prefix (addoff adds the final rowstart).
__global__ __launch_bounds__(256) void scan1_k(const int* __restrict__ deg8,
                                               int* __restrict__ deg,
                                               int* __restrict__ rowstart,
                                               int* __restrict__ base8,
                                               int* __restrict__ bsum, int n, int N) {
    __shared__ int s[256];
    int tid = threadIdx.x;
    int i = blockIdx.x * 256 + tid;
    int pre[8];
    int v = 0;
    #pragma unroll
    for (int c = 0; c < 8; ++c) {
        int t = (i < n) ? deg8[(size_t)c * N + i] : 0;
        pre[c] = v;
        v += t;
    }
    s[tid] = v;
    __syncthreads();
    for (int off = 1; off < 256; off <<= 1) {
        int t = (tid >= off) ? s[tid - off] : 0;
        __syncthreads();
        s[tid] += t;
        __syncthreads();
    }
    if (i < n) {
        rowstart[i] = s[tid] - v;                 // exclusive within block
        deg[i] = v;
        #pragma unroll
        for (int c = 0; c < 8; ++c) base8[(size_t)i * 8 + c] = pre[c];
    }
    if (tid == 255) bsum[blockIdx.x] = s[255];
}

__global__ __launch_bounds__(256) void scan2_k(int* __restrict__ bsum, int nb) {
    __shared__ int s[256];
    int tid = threadIdx.x;
    int v = (tid < nb) ? bsum[tid] : 0;
    s[tid] = v;
    __syncthreads();
    for (int off = 1; off < 256; off <<= 1) {
        int t = (tid >= off) ? s[tid - off] : 0;
        __syncthreads();
        s[tid] += t;
        __syncthreads();
    }
    if (tid < nb) bsum[tid] = s[tid] - v;
}

// rowstart += block offset; base8[i][c] += final rowstart
__global__ void addoff_k(int* __restrict__ rowstart, const int* __restrict__ bsum,
                         int* __restrict__ base8, int n) {
    int i = blockIdx.x * blockDim.x + threadIdx.x;
    if (i < n) {
        int rs = rowstart[i] + bsum[blockIdx.x];
        rowstart[i] = rs;
        #pragma unroll
        for (int c = 0; c < 8; ++c) base8[(size_t)i * 8 + c] += rs;
    }
}

// --- atomic-free CSR fill, dst-range partitioned for write locality -------
// slot = base8[d][chunk-class(e)] + rank[e]; chunk-class(e) = (e>>8)&7.
__global__ __launch_bounds__(256) void fill_swz_k(
        const int* __restrict__ src, const int* __restrict__ dst,
        const int* __restrict__ base8, const int* __restrict__ rank,
        int* __restrict__ csr, int nE, int rngSize) {
    int cls = blockIdx.x & 7;
    int lo = cls * rngSize, hi = lo + rngSize;
    int nb = gridDim.x >> 3;
    int bi = blockIdx.x >> 3;
    for (int e = bi * 256 + threadIdx.x; e < nE; e += nb * 256) {
        int d = dst[e];
        if (d >= lo && d < hi) {
            int cc = (e >> 8) & 7;
            csr[base8[(size_t)d * 8 + cc] + rank[e]] = src[e];
        }
    }
}

// --- uint4 gather-mean: one wave per node ----------------------------------
__global__ __launch_bounds__(256) void gather_v4_k(
        const uint4* __restrict__ feat,           // [n][16] uint4 (256B rows)
        const int* __restrict__ csr, const int* __restrict__ rowstart,
        const int* __restrict__ deg, uint4* __restrict__ outr, int n) {
    int node = blockIdx.x * 4 + (threadIdx.x >> 6);
    if (node >= n) return;
    int lane = threadIdx.x & 63;
    int es = lane >> 4;                           // edge slot
    int cs = lane & 15;                           // uint4 col slot
    int s0 = rowstart[node], dc = deg[node];

    float acc[8] = {0.f, 0.f, 0.f, 0.f, 0.f, 0.f, 0.f, 0.f};
    int base = 0;
    int i0 = 0, i1 = 0, i2 = 0, i3 = 0;
    if (base + 16 <= dc) {
        i0 = csr[s0 + es];
        i1 = csr[s0 + 4 + es];
        i2 = csr[s0 + 8 + es];
        i3 = csr[s0 + 12 + es];
    }
    while (base + 16 <= dc) {
        uint4 w0 = feat[(size_t)i0 * 16 + cs];
        uint4 w1 = feat[(size_t)i1 * 16 + cs];
        uint4 w2 = feat[(size_t)i2 * 16 + cs];
        uint4 w3 = feat[(size_t)i3 * 16 + cs];
        base += 16;
        if (base + 16 <= dc) {                    // prefetch next indices
            i0 = csr[s0 + base + es];
            i1 = csr[s0 + base + 4 + es];
            i2 = csr[s0 + base + 8 + es];
            i3 = csr[s0 + base + 12 + es];
        }
        acc8(acc, w0);
        acc8(acc, w1);
        acc8(acc, w2);
        acc8(acc, w3);
    }
    if (base < dc) {                              // masked tail
        int c = dc - 1;
        int e0 = base + es, e1 = base + 4 + es, e2 = base + 8 + es, e3 = base + 12 + es;
        int t0 = csr[s0 + min(e0, c)];
        int t1 = csr[s0 + min(e1, c)];
        int t2 = csr[s0 + min(e2, c)];
        int t3 = csr[s0 + min(e3, c)];
        uint4 w0 = feat[(size_t)t0 * 16 + cs];
        uint4 w1 = feat[(size_t)t1 * 16 + cs];
        uint4 w2 = feat[(size_t)t2 * 16 + cs];
        uint4 w3 = feat[(size_t)t3 * 16 + cs];
        acc8m(acc, w0, (e0 < dc) ? 1.0f : 0.0f);
        acc8m(acc, w1, (e1 < dc) ? 1.0f : 0.0f);
        acc8m(acc, w2, (e2 < dc) ? 1.0f : 0.0f);
        acc8m(acc, w3, (e3 < dc) ? 1.0f : 0.0f);
    }

    // reduce across the 4 edge slots (lane bits 4,5)
    #pragma unroll
    for (int k = 0; k < 8; ++k) {
        acc[k] += __shfl_xor(acc[k], 16, 64);
        acc[k] += __shfl_xor(acc[k], 32, 64);
    }

    if (es == 0) {
        float inv = (dc > 0) ? 1.0f / (float)dc : 0.0f;
        uint4 o;
        o.x = ((unsigned)f2bf(acc[1] * inv) << 16) | (unsigned)f2bf(acc[0] * inv);
        o.y = ((unsigned)f2bf(acc[3] * inv) << 16) | (unsigned)f2bf(acc[2] * inv);
        o.z = ((unsigned)f2bf(acc[5] * inv) << 16) | (unsigned)f2bf(acc[4] * inv);
        o.w = ((unsigned)f2bf(acc[7] * inv) << 16) | (unsigned)f2bf(acc[6] * inv);
        outr[(size_t)node * 16 + cs] = o;
    }
}

// --- fused SAGE GEMM: out = relu([A|R] @ Wpack + bias), bf16 MFMA ----------
__global__ __launch_bounds__(256) void gemm_mfma_k(
        const unsigned short* __restrict__ A,     // aggr [n][128] bf16
        const unsigned short* __restrict__ R,     // root [n][128] bf16
        const unsigned short* __restrict__ wp,    // packed weights
        const float* __restrict__ bias,           // [128] f32
        unsigned short* __restrict__ outp,        // [n][128] bf16
        int n) {
    int tid = threadIdx.x;
    int wave = tid >> 6, lane = tid & 63;
    int rowTile = blockIdx.x * 64 + wave * 16;
    int lrow = lane & 15, lk = lane >> 4;

    int arow = rowTile + lrow;
    if (arow >= n) arow = n - 1;                  // clamp; stores are guarded

    bf16x8 a[8];
    const unsigned short* abase = A + (size_t)arow * FDIM + lk * 8;
    const unsigned short* rbase = R + (size_t)arow * FDIM + lk * 8;
    #pragma unroll
    for (int s = 0; s < 4; ++s) a[s] = *(const bf16x8*)(abase + s * 32);
    #pragma unroll
    for (int s = 0; s < 4; ++s) a[4 + s] = *(const bf16x8*)(rbase + s * 32);

    const bf16x8* bp = (const bf16x8*)wp;
    int ocol = lane & 15;
    int orow0 = rowTile + (lane >> 4) * 4;

    #pragma unroll
    for (int nt = 0; nt < 8; ++nt) {
        float bv = bias[nt * 16 + ocol];
        f32x4 acc = {bv, bv, bv, bv};
        #pragma unroll
        for (int s = 0; s < 8; ++s) {
            bf16x8 b = bp[(nt * 8 + s) * 64 + lane];
            acc = __builtin_amdgcn_mfma_f32_16x16x32_bf16(a[s], b, acc, 0, 0, 0);
        }
        #pragma unroll
        for (int r = 0; r < 4; ++r) {
            int orow = orow0 + r;
            if (orow < n) {
                float v = fmaxf(acc[r], 0.0f);
                outp[(size_t)orow * FDIM + nt * 16 + ocol] = f2bf(v);
            }
        }
    }
}

// --- segmented global mean pool: 64 nodes/block, batch sorted --------------
__global__ __launch_bounds__(256) void pool_seg_k(
        const unsigned short* __restrict__ h,     // [nN][128] bf16
        const int* __restrict__ batch,
        float* __restrict__ gsum, int* __restrict__ gcnt, int nN) {
    __shared__ int bw[64];
    __shared__ float red[8][32][4];
    int base = blockIdx.x * 64;
    if (base >= nN) return;
    int tid = threadIdx.x;
    int rg = tid >> 5, cs = tid & 31;
    int cnt = min(64, nN - base);
    if (tid < 64) bw[tid] = batch[min(base + tid, nN - 1)];
    __syncthreads();
    int g0 = bw[0], g1 = bw[cnt - 1];

    for (int g = g0; g <= g1; ++g) {
        int s = 0;
        while (s < cnt && bw[s] < g) ++s;
        int e = s;
        while (e < cnt && bw[e] == g) ++e;

        float a0 = 0.f, a1 = 0.f, a2 = 0.f, a3 = 0.f;
        for (int i = s + rg; i < e; i += 8) {
            uint2 v = ((const uint2*)(h + (size_t)(base + i) * FDIM))[cs];
            a0 += bf2f((unsigned short)(v.x & 0xffff));
            a1 += bf2f((unsigned short)(v.x >> 16));
            a2 += bf2f((unsigned short)(v.y & 0xffff));
            a3 += bf2f((unsigned short)(v.y >> 16));
        }
        red[rg][cs][0] = a0; red[rg][cs][1] = a1;
        red[rg][cs][2] = a2; red[rg][cs][3] = a3;
        __syncthreads();
        if (rg == 0 && e > s) {
            #pragma unroll
            for (int r = 1; r < 8; ++r) {
                a0 += red[r][cs][0]; a1 += red[r][cs][1];
                a2 += red[r][cs][2]; a3 += red[r][cs][3];
            }
            float* go = gsum + (size_t)g * FDIM + cs * 4;
            atomicAdd(go + 0, a0);
            atomicAdd(go + 1, a1);
            atomicAdd(go + 2, a2);
            atomicAdd(go + 3, a3);
            if (cs == 0) atomicAdd(&gcnt[g], e - s);
        }
        __syncthreads();
    }
}

// --- head: logits = mean @ wf + bf ; log_softmax ---------------------------
__global__ __launch_bounds__(128) void head_k(const float* __restrict__ gsum,
                                              const int* __restrict__ gcnt,
                                              const float* __restrict__ wf,
                                              const float* __restrict__ bf,
                                              float* __restrict__ out, int nG) {
    int g = blockIdx.x;
    if (g >= nG) return;
    __shared__ float row[FDIM];
    int tid = threadIdx.x;
    float inv = 1.0f / fmaxf((float)gcnt[g], 1.0f);
    row[tid] = gsum[(size_t)g * FDIM + tid] * inv;
    __syncthreads();

    float logit = -1e30f;
    if (tid < 16) {
        logit = bf[tid];
        for (int k = 0; k < FDIM; ++k) logit += row[k] * wf[k * 16 + tid];
    }
    float m = logit;
    for (int off = 8; off >= 1; off >>= 1) m = fmaxf(m, __shfl_xor(m, off, 64));
    float ev = (tid < 16) ? expf(logit - m) : 0.0f;
    float sum = ev;
    for (int off = 8; off >= 1; off >>= 1) sum += __shfl_xor(sum, off, 64);
    if (tid < 16) out[(size_t)g * 16 + tid] = logit - m - logf(sum);
}

extern "C" void kernel_launch(void* const* d_in, const int* in_sizes, int n_in,
                              void* d_out, int out_size, void* d_ws, size_t ws_size,
                              hipStream_t stream) {
    const float* x    = (const float*)d_in[0];
    const int*   ei   = (const int*)d_in[1];
    const int*   batch= (const int*)d_in[2];
    const float* w1l  = (const float*)d_in[3];
    const float* b1   = (const float*)d_in[4];
    const float* w1r  = (const float*)d_in[5];
    const float* w2l  = (const float*)d_in[6];
    const float* b2   = (const float*)d_in[7];
    const float* w2r  = (const float*)d_in[8];
    const float* wf   = (const float*)d_in[9];
    const float* bf   = (const float*)d_in[10];
    float* out = (float*)d_out;

    const int N = in_sizes[0] / FDIM;
    const int E = in_sizes[1] / 2;
    const int G = out_size / 16;
    const int* src = ei;
    const int* dst = ei + E;
    const int NB = (N + 255) / 256;              // <= 256 for scan2_k

    // --- workspace layout ---
    char* ws = (char*)d_ws;
    size_t off = 0;
    auto alloc = [&](size_t bytes) { void* p = ws + off; off = (off + bytes + 255) & ~(size_t)255; return p; };
    unsigned short* xb   = (unsigned short*)alloc((size_t)N * FDIM * 2); // also h2
    unsigned short* aggr = (unsigned short*)alloc((size_t)N * FDIM * 2);
    unsigned short* h1   = (unsigned short*)alloc((size_t)N * FDIM * 2);
    unsigned short* wp1  = (unsigned short*)alloc(8 * 8 * 64 * 8 * 2);
    unsigned short* wp2  = (unsigned short*)alloc(8 * 8 * 64 * 8 * 2);
    int* deg8     = (int*)alloc((size_t)8 * N * sizeof(int));
    int* base8    = (int*)alloc((size_t)N * 8 * sizeof(int));
    int* deg      = (int*)alloc((size_t)N * sizeof(int));
    int* rowstart = (int*)alloc((size_t)N * sizeof(int));
    int* bsum     = (int*)alloc(256 * sizeof(int));
    int* csr      = (int*)alloc((size_t)E * sizeof(int));
    int* rank     = (int*)alloc((size_t)E * sizeof(int));
    float* gsum   = (float*)alloc((size_t)G * FDIM * sizeof(float));
    int*   gcnt   = (int*)alloc((size_t)G * sizeof(int));
    unsigned short* h2 = xb;                      // xb dead once h2 is written

    // --- zero accumulators ---
    hipMemsetAsync(deg8, 0, (size_t)8 * N * sizeof(int), stream);
    hipMemsetAsync(gsum, 0, (size_t)G * FDIM * sizeof(float), stream);
    hipMemsetAsync(gcnt, 0, (size_t)G * sizeof(int), stream);

    // --- merged prep: privatized deg/rank | cvt | packs ---
    const int nbE = (E + 255) / 256;
    const int nbC = (N * FDIM / 4 + 255) / 256;
    prep_k<<<nbE + nbC + 32, 256, 0, stream>>>(dst, deg8, rank, E, N,
                                               x, xb, N * FDIM / 4,
                                               w1l, w1r, wp1, w2l, w2r, wp2,
                                               nbE, nbC);

    // --- CSR offsets + localized atomic-free fill ---
    scan1_k<<<NB, 256, 0, stream>>>(deg8, deg, rowstart, base8, bsum, N, N);
    scan2_k<<<1, 256, 0, stream>>>(bsum, NB);
    addoff_k<<<NB, 256, 0, stream>>>(rowstart, bsum, base8, N);
    {
        int rngSize = (N + 7) / 8;
        fill_swz_k<<<2048, 256, 0, stream>>>(src, dst, base8, rank, csr, E, rngSize);
    }

    // --- layer 1 ---
    gather_v4_k<<<(N + 3) / 4, 256, 0, stream>>>((const uint4*)xb, csr, rowstart, deg,
                                                 (uint4*)aggr, N);
    gemm_mfma_k<<<(N + 63) / 64, 256, 0, stream>>>(aggr, xb, wp1, b1, h1, N);

    // --- layer 2 ---
    gather_v4_k<<<(N + 3) / 4, 256, 0, stream>>>((const uint4*)h1, csr, rowstart, deg,
                                                 (uint4*)aggr, N);
    gemm_mfma_k<<<(N + 63) / 64, 256, 0, stream>>>(aggr, h1, wp2, b2, h2, N);

    // --- pool + head ---
    pool_seg_k<<<(N + 63) / 64, 256, 0, stream>>>(h2, batch, gsum, gcnt, N);
    head_k<<<G, 128, 0, stream>>>(gsum, gcnt, wf, bf, out, G);
}